// Round 4
// baseline (630.281 us; speedup 1.0000x reference)
//
#include <hip/hip_runtime.h>

// Problem constants (from reference)
#define BATCH 2048
#define T 512
#define NF 10
#define HID 30
#define S3T 1536          // 3*T sequence length after reshape/transpose
#define FEAT_PER_B 15360  // 10*1536 features per batch element
// Workspace: BATCH * FEAT_PER_B * 2 = 62,914,560 bytes (f16 xpair)
// Layout: xpair[b][p][s][e] (p<5, s<1536, e<2) = f16 x[b][s][2p+e].
// One uint4 (16B) at stream p, chunk c = d-pair (2p,2p+1) for steps 4c..4c+3.

typedef _Float16 v2h __attribute__((ext_vector_type(2)));

#define LOG2E 1.44269504088896f

__device__ __forceinline__ float fexp(float x) {
    return __builtin_amdgcn_exp2f(x * LOG2E);   // v_exp_f32
}
__device__ __forceinline__ float frcp(float x) {
    return __builtin_amdgcn_rcpf(x);            // v_rcp_f32
}

// DPP ctrl encodings
#define DPP_QPERM_XOR1 0xB1   // quad_perm [1,0,3,2]
#define DPP_ROR2       0x122  // row_ror:2  (1 pair)
#define DPP_ROR4       0x124  // row_ror:4  (2 pairs)
#define DPP_ROR8       0x128  // row_ror:8  (4 pairs)

template <int CTRL>
__device__ __forceinline__ unsigned dppmov(unsigned v) {
    return (unsigned)__builtin_amdgcn_update_dpp(0, (int)v, CTRL, 0xF, 0xF,
                                                 false);
}

// R19-verified combine: own partial + lane(+-32) partial on BOTH lanes.
// permlane32_swap is VALU (~2cyc), not the DS pipe.
__device__ __forceinline__ float half_sum(float a) {
    unsigned ua = __builtin_bit_cast(unsigned, a);
    auto r = __builtin_amdgcn_permlane32_swap(ua, ua, false, false);
    return __builtin_bit_cast(float, (unsigned)r[0]) +
           __builtin_bit_cast(float, (unsigned)r[1]);
}

// Kernel 1: transpose-through-LDS [R15: 89 -> ~19us], f16 out [R16].
__global__ void __launch_bounds__(512)
feat_kernel(const int* __restrict__ atom_i,
            const int* __restrict__ atom_j,
            const float* __restrict__ dist,
            const float* __restrict__ emb,
            uint4* __restrict__ xpair8) {
    __shared__ float lf[512 * 31 + 30];   // slot(t,c) = t*31 + c
    const int b = blockIdx.x;
    const int t = threadIdx.x;

    {
        const int bt = b * T + t;
        const int ai = atom_i[bt];
        const int aj = atom_j[bt];
        const float dd = dist[bt];
        const float mi = (ai != 0) ? 1.0f : 0.0f;
        const float mj = (aj != 0) ? 1.0f : 0.0f;
        const float* ei = &emb[ai * NF];
        const float* ej = &emb[aj * NF];
        float* row = &lf[t * 31];
#pragma unroll
        for (int c = 0; c < NF; ++c) row[c] = mi * ei[c];
#pragma unroll
        for (int c = 0; c < NF; ++c) row[10 + c] = mj * ej[c];
#pragma unroll
        for (int c = 0; c < NF; ++c) {
            float ctr = (float)(c + 1) * 0.7f;
            float df = ctr - dd;
            row[20 + c] = mi * fexp(-df * df);
        }
    }
    __syncthreads();

    uint4* ob = xpair8 + (long)b * 1920;
    for (int o = t; o < 1920; o += 512) {
        unsigned p  = (unsigned)o / 384u;
        unsigned c4 = (unsigned)o - p * 384u;
        union { _Float16 h[8]; uint4 u; } pk;
#pragma unroll
        for (int kx = 0; kx < 8; ++kx) {
            unsigned s = 4u * c4 + (unsigned)(kx >> 1);
            unsigned e = (unsigned)(kx & 1);
            unsigned f = (2u * p + e) * 1536u + s;
            unsigned tt = f / 30u;            // compiler -> magic mul
            unsigned cc = f - tt * 30u;
            pk.h[kx] = (_Float16)lf[tt * 31u + cc];
        }
        ob[o] = pk.u;
    }
}

// One GRU step (R22): split-K across wave halves + register h-gather.
// Lane x and x+32 both own unit (x&31) of the wave's single batch; half0
// accumulates hh pairs 0-7 + ih pairs 0-2 (+ biases), half1 hh pairs 8-15
// (pair 15 zero-weighted) + ih pairs 3-4 (+pad). Dot chains are 8 deep
// (was 21). Gather: cvt h->f16, quad-perm pack -> per-lane pair, ONE
// permlane16_swap + runtime-discovered cndmask (own-row vs swapped-row,
// constant per lane), 7 row-rors -> the 8 pairs of this half's K-range.
// Combine via 4 half_sums (permlane32: lanes x <-> x+32 = exactly where
// unit x's two partials live). NO LDS, no fences; all inter-step deps are
// register deps. ih dots issue first (independent of h) to fill the gather
// latency; program order puts hh dots after their gather slots.
#define STEP(XQ, IDX)                                                        \
    {                                                                        \
        v2h xc[3];                                                           \
        _Pragma("unroll")                                                    \
        for (int pp = 0; pp < 3; ++pp) {                                     \
            unsigned w = ((const unsigned*)&XQ[pp])[IDX];                    \
            __builtin_memcpy(&xc[pp], &w, 4);                                \
        }                                                                    \
        float ar = brf, az = bzf, ai = bif, ah = bhf;                        \
        _Pragma("unroll")                                                    \
        for (int d = 0; d < 3; ++d) {                                        \
            ar = __builtin_amdgcn_fdot2(wir[d], xc[d], ar, false);           \
            az = __builtin_amdgcn_fdot2(wiz[d], xc[d], az, false);           \
            ai = __builtin_amdgcn_fdot2(win[d], xc[d], ai, false);           \
        }                                                                    \
        unsigned hf = (unsigned)__builtin_bit_cast(unsigned short,           \
                                                   (_Float16)h);             \
        unsigned nb = dppmov<DPP_QPERM_XOR1>(hf);                            \
        unsigned g0 = hf | (nb << 16);                                       \
        auto rr = __builtin_amdgcn_permlane16_swap((unsigned)g0,             \
                                                   (unsigned)g0,             \
                                                   false, false);            \
        unsigned sel = selOwn ? (unsigned)rr[0] : (unsigned)rr[1];           \
        unsigned s1 = dppmov<DPP_ROR2>(sel);                                 \
        unsigned s2 = dppmov<DPP_ROR4>(sel);                                 \
        unsigned s3 = dppmov<DPP_ROR4>(s1);                                  \
        unsigned s4 = dppmov<DPP_ROR8>(sel);                                 \
        unsigned s5 = dppmov<DPP_ROR8>(s1);                                  \
        unsigned s6 = dppmov<DPP_ROR8>(s2);                                  \
        unsigned s7 = dppmov<DPP_ROR8>(s3);                                  \
        unsigned ss[8] = {sel, s1, s2, s3, s4, s5, s6, s7};                  \
        _Pragma("unroll")                                                    \
        for (int j = 0; j < 8; ++j) {                                        \
            v2h hj = __builtin_bit_cast(v2h, ss[j]);                         \
            ar = __builtin_amdgcn_fdot2(whr[j], hj, ar, false);              \
            az = __builtin_amdgcn_fdot2(whz[j], hj, az, false);              \
            ah = __builtin_amdgcn_fdot2(whn[j], hj, ah, false);              \
        }                                                                    \
        ar = half_sum(ar); az = half_sum(az);                                \
        ai = half_sum(ai); ah = half_sum(ah);                                \
        float er = __builtin_amdgcn_exp2f(ar);                               \
        float ez = __builtin_amdgcn_exp2f(az);                               \
        float rg = frcp(1.0f + er);                                          \
        float zg = frcp(1.0f + ez);                                          \
        float ng =                                                           \
            2.0f * frcp(1.0f + __builtin_amdgcn_exp2f(ai + rg * ah)) - 1.0f; \
        h = ng + zg * (h - ng);                                              \
    }

// Kernel 2: GRU recurrence — R22: 1 batch/wave, 2048 single-wave blocks ->
// 2 waves/SIMD (the R19 occupancy structure) so the ~250-cyc serial chain
// (gather + 8-deep dot chain + 4-serial-trans) of one wave hides under the
// other wave's issue; combined with the R20 register gather (no LDS) and
// split-K halving per-wave dot issue to 33/step. R20 measured the solo
// chain stall at ~400 cyc/step (VALUBusy-calibrated); R19 measured that
// 2-wave co-residency works but was throttled by its LDS round trip. This
// kernel is the cross product. waves_per_eu(2,2): VGPR cap 256, usage
// ~100 -> both waves' weights stay resident.
__attribute__((amdgpu_waves_per_eu(2, 2)))
__global__ void __launch_bounds__(64)
gru_kernel(const _Float16* __restrict__ xpair,
           const float* __restrict__ W_ih,   // [90,10]
           const float* __restrict__ W_hh,   // [90,30]
           const float* __restrict__ b_ih,   // [90]
           const float* __restrict__ b_hh,   // [90]
           const float* __restrict__ W_out,  // [1,30]
           const float* __restrict__ b_out,  // [1]
           float* __restrict__ out) {
    const int lane = threadIdx.x;
    const int half = lane >> 5;        // K-half: 0 -> pairs 0-7, 1 -> 8-15
    const int k    = lane & 31;        // unit owned by this lane
    const bool active = (k < HID);
    const int kk = active ? k : (HID - 1);
    const int b = blockIdx.x;

    const float SRZ = -LOG2E;          // sigmoid(x) = rcp(1+exp2(-L x))
    const float SN  = -2.0f * LOG2E;   // tanh(u) = 2 rcp(1+exp2(-2L u)) - 1

    // Discover the gather network's behavior on integer pair labels.
    // Lane holds h_{lane&31} -> pair label (lane&31)>>1. After the swap,
    // one of rr[0]/rr[1] carries a row whose 16 labels are exactly this
    // half's K-range [8*half, 8*half+8) (adjacent rows hold complementary
    // ranges); selOwn records which, per lane (constant across steps).
    // pidx[i] = which pair lands in gather slot i after the rors.
    int pidx[8];
    int selOwn;
    {
        const unsigned lo = (unsigned)(half << 3);
        unsigned lab = (unsigned)((lane & 31) >> 1);
        auto rr = __builtin_amdgcn_permlane16_swap((unsigned)lab,
                                                   (unsigned)lab,
                                                   false, false);
        unsigned l0 = (unsigned)rr[0], l1 = (unsigned)rr[1];
        const bool own0 = (l0 - lo) < 8u;
        selOwn = own0 ? 1 : 0;
        unsigned sel = own0 ? l0 : l1;
        unsigned s1 = dppmov<DPP_ROR2>(sel);
        unsigned s2 = dppmov<DPP_ROR4>(sel);
        unsigned s3 = dppmov<DPP_ROR4>(s1);
        unsigned s4 = dppmov<DPP_ROR8>(sel);
        unsigned s5 = dppmov<DPP_ROR8>(s1);
        unsigned s6 = dppmov<DPP_ROR8>(s2);
        unsigned s7 = dppmov<DPP_ROR8>(s3);
        pidx[0] = (int)sel; pidx[1] = (int)s1; pidx[2] = (int)s2;
        pidx[3] = (int)s3;  pidx[4] = (int)s4; pidx[5] = (int)s5;
        pidx[6] = (int)s6;  pidx[7] = (int)s7;
    }

    // hh weights: 8 v2h per gate = this half's K-range pairs, ordered by
    // pidx, intra-pair order swapped on odd lanes (rors shift by even lane
    // counts and the row-swap is vertical, so source parity == own parity;
    // fdot2 is symmetric). Out-of-range or pair-15 slots get zero weights.
    // Prescaled f32 (log2e folding: r/z x(-L), n x(-2L)) then RNE->f16.
    v2h whr[8], whz[8], whn[8];
    {
        const float* Rr = &W_hh[(0 * HID + kk) * HID];
        const float* Rz = &W_hh[(1 * HID + kk) * HID];
        const float* Rn = &W_hh[(2 * HID + kk) * HID];
        const unsigned lo = (unsigned)(half << 3);
        const bool odd = (lane & 1) != 0;
#pragma unroll
        for (int i = 0; i < 8; ++i) {
            const unsigned p = (unsigned)pidx[i];
            const bool valid = ((p - lo) < 8u) && (p < 15u);
            const int c = valid ? (int)(2u * p) : 0;
            const float srz = valid ? SRZ : 0.0f;
            const float sn  = valid ? SN  : 0.0f;
            float r0 = Rr[c] * srz, r1 = Rr[c + 1] * srz;
            float z0 = Rz[c] * srz, z1 = Rz[c + 1] * srz;
            float n0 = Rn[c] * sn,  n1 = Rn[c + 1] * sn;
            if (odd) {
                float tt;
                tt = r0; r0 = r1; r1 = tt;
                tt = z0; z0 = z1; z1 = tt;
                tt = n0; n0 = n1; n1 = tt;
            }
            whr[i] = (v2h){(_Float16)r0, (_Float16)r1};
            whz[i] = (v2h){(_Float16)z0, (_Float16)z1};
            whn[i] = (v2h){(_Float16)n0, (_Float16)n1};
        }
    }
    // ih weights: 3 v2h per gate = d-pairs half*3 .. +2 (pair 5 = zero pad).
    v2h wir[3], wiz[3], win[3];
    const int db = half * 3;
    {
        const float* Rr = &W_ih[(0 * HID + kk) * NF];
        const float* Rz = &W_ih[(1 * HID + kk) * NF];
        const float* Rn = &W_ih[(2 * HID + kk) * NF];
#pragma unroll
        for (int i = 0; i < 3; ++i) {
            const int d  = db + i;
            const int dd = (d < 5) ? d * 2 : 0;
            const float mrz = (d < 5) ? SRZ : 0.0f;
            const float mn  = (d < 5) ? SN  : 0.0f;
            wir[i] = (v2h){(_Float16)(Rr[dd] * mrz), (_Float16)(Rr[dd + 1] * mrz)};
            wiz[i] = (v2h){(_Float16)(Rz[dd] * mrz), (_Float16)(Rz[dd + 1] * mrz)};
            win[i] = (v2h){(_Float16)(Rn[dd] * mn),  (_Float16)(Rn[dd + 1] * mn)};
        }
    }
    // Biases: counted ONCE per combined sum -> seed half0 only.
    const float en  = (half == 0) ? 1.0f : 0.0f;
    const float brf = en * SRZ * (b_ih[0 * HID + kk] + b_hh[0 * HID + kk]);
    const float bzf = en * SRZ * (b_ih[1 * HID + kk] + b_hh[1 * HID + kk]);
    const float bif = en * SN * b_ih[2 * HID + kk];  // n biases stay split:
    const float bhf = en * SN * b_hh[2 * HID + kk];  // n uses ai + rg*ah

    // 3 chunk streams per lane: half0 uses d-pair streams {0,1,2}, half1
    // {3,4,4-dup} (dup multiplied by the zero pad weight).
    const _Float16* xb = xpair + (long)b * FEAT_PER_B;
    const uint4* xa[3];
#pragma unroll
    for (int i = 0; i < 3; ++i) {
        int s = db + i;
        if (s > 4) s = 4;
        xa[i] = (const uint4*)(xb + s * 3072);
    }

    float h = 0.0f;
    uint4 xq0[3], xq1[3];
#pragma unroll
    for (int p = 0; p < 3; ++p) xq0[p] = xa[p][0];

    // 384 chunks of 4 steps, ping-pong pairs (xq0/xq1 alternate roles — no
    // register rotation [R18]). 384 is even; prefetch c2+1 always in range,
    // tail prefetch c2+2 clamps to 383.
    for (int c2 = 0; c2 < 384; c2 += 2) {
#pragma unroll
        for (int p = 0; p < 3; ++p) xq1[p] = xa[p][c2 + 1];
        STEP(xq0, 0);
        STEP(xq0, 1);
        STEP(xq0, 2);
        STEP(xq0, 3);
        const int cn = (c2 + 2 < 384) ? (c2 + 2) : 383;
#pragma unroll
        for (int p = 0; p < 3; ++p) xq0[p] = xa[p][cn];
        STEP(xq1, 0);
        STEP(xq1, 1);
        STEP(xq1, 2);
        STEP(xq1, 3);
    }

    // out[b] = relu(h . W_out + b_out); both halves hold identical h ->
    // reduce the lower half only.
    float v = (active && half == 0) ? h * W_out[kk] : 0.0f;
#pragma unroll
    for (int off = 16; off; off >>= 1) v += __shfl_xor(v, off, 32);
    if (lane == 0) {
        float o = v + b_out[0];
        out[b] = o > 0.0f ? o : 0.0f;
    }
}

extern "C" void kernel_launch(void* const* d_in, const int* in_sizes, int n_in,
                              void* d_out, int out_size, void* d_ws, size_t ws_size,
                              hipStream_t stream) {
    const int* atom_i   = (const int*)d_in[0];
    const int* atom_j   = (const int*)d_in[1];
    const float* dist   = (const float*)d_in[2];
    const float* emb    = (const float*)d_in[3];
    const float* W_ih   = (const float*)d_in[4];
    const float* W_hh   = (const float*)d_in[5];
    const float* b_ih   = (const float*)d_in[6];
    const float* b_hh   = (const float*)d_in[7];
    const float* W_out  = (const float*)d_in[8];
    const float* b_out  = (const float*)d_in[9];
    float* out = (float*)d_out;
    _Float16* xpair = (_Float16*)d_ws;   // 62,914,560 B

    feat_kernel<<<BATCH, 512, 0, stream>>>(atom_i, atom_j, dist, emb,
                                           (uint4*)xpair);
    gru_kernel<<<BATCH, 64, 0, stream>>>(xpair, W_ih, W_hh, b_ih, b_hh,
                                         W_out, b_out, out);
}

// Round 5
// 427.377 us; speedup vs baseline: 1.4748x; 1.4748x over previous
//
#include <hip/hip_runtime.h>

// Problem constants (from reference)
#define BATCH 2048
#define T 512
#define NF 10
#define HID 30
#define S3T 1536          // 3*T sequence length after reshape/transpose
#define FEAT_PER_B 15360  // 10*1536 features per batch element
// Workspace: BATCH * FEAT_PER_B * 2 = 62,914,560 bytes (f16 xpair)
// Layout: xpair[b][p][s][e] (p<5, s<1536, e<2) = f16 x[b][s][2p+e].
// One uint4 (16B) at stream p, chunk c = d-pair (2p,2p+1) for steps 4c..4c+3.

typedef _Float16 v2h __attribute__((ext_vector_type(2)));

#define LOG2E 1.44269504088896f

__device__ __forceinline__ float fexp(float x) {
    return __builtin_amdgcn_exp2f(x * LOG2E);   // v_exp_f32
}
__device__ __forceinline__ float frcp(float x) {
    return __builtin_amdgcn_rcpf(x);            // v_rcp_f32
}

// R19-R22 post-mortem (kept as session ledger):
//  - real VALU busy = VALUBusy/2 (gfx94x SIMD-16 formula on SIMD-32 HW);
//    R18=94 busy/batch-step (best), split-K=162, reg-gather=144/209.
//  - DPP/permlane crossbar ops cost ~6.5 issue cyc each (fit across R20 &
//    R22) -> register h-broadcast loses to the LDS round trip on issue.
//  - 2 waves/SIMD never overlapped (R19/R22 per-wave wall > solo chain):
//    co-resident waves interfere. Keep 1 wave/SIMD, all 1024 SIMDs.
// R23: R18 verbatim except the dot accumulation is reassociated into
// parallel sub-chains (tree), cutting the 20-deep serial fdot2 chain
// (~12 cyc dep latency each) to 5-deep + 2 adds.

// Kernel 1: transpose-through-LDS [R15: 89 -> ~19us], f16 out [R16].
__global__ void __launch_bounds__(512)
feat_kernel(const int* __restrict__ atom_i,
            const int* __restrict__ atom_j,
            const float* __restrict__ dist,
            const float* __restrict__ emb,
            uint4* __restrict__ xpair8) {
    __shared__ float lf[512 * 31 + 30];   // slot(t,c) = t*31 + c
    const int b = blockIdx.x;
    const int t = threadIdx.x;

    {
        const int bt = b * T + t;
        const int ai = atom_i[bt];
        const int aj = atom_j[bt];
        const float dd = dist[bt];
        const float mi = (ai != 0) ? 1.0f : 0.0f;
        const float mj = (aj != 0) ? 1.0f : 0.0f;
        const float* ei = &emb[ai * NF];
        const float* ej = &emb[aj * NF];
        float* row = &lf[t * 31];
#pragma unroll
        for (int c = 0; c < NF; ++c) row[c] = mi * ei[c];
#pragma unroll
        for (int c = 0; c < NF; ++c) row[10 + c] = mj * ej[c];
#pragma unroll
        for (int c = 0; c < NF; ++c) {
            float ctr = (float)(c + 1) * 0.7f;
            float df = ctr - dd;
            row[20 + c] = mi * fexp(-df * df);
        }
    }
    __syncthreads();

    uint4* ob = xpair8 + (long)b * 1920;
    for (int o = t; o < 1920; o += 512) {
        unsigned p  = (unsigned)o / 384u;
        unsigned c4 = (unsigned)o - p * 384u;
        union { _Float16 h[8]; uint4 u; } pk;
#pragma unroll
        for (int kx = 0; kx < 8; ++kx) {
            unsigned s = 4u * c4 + (unsigned)(kx >> 1);
            unsigned e = (unsigned)(kx & 1);
            unsigned f = (2u * p + e) * 1536u + s;
            unsigned tt = f / 30u;            // compiler -> magic mul
            unsigned cc = f - tt * 30u;
            pk.h[kx] = (_Float16)lf[tt * 31u + cc];
        }
        ob[o] = pk.u;
    }
}

// One GRU step: reads hbuf16[PAR], writes hbuf16[PAR^1]. XQ = 5 uint4 chunk
// regs (4 steps of d-pairs); IDX in 0..3 selects the step's 32-bit word.
// R23 tree accumulation: per gate 4 independent accumulators —
//   r: ar0(bias+5 ih, issues during the ds-wait) + ar1/ar2/ar3 (5 hh each)
//   z: likewise; n: ai(bias+5 ih) separate, ah0(bias+5 hh)+ah1+ah2.
// Sub-chain j-ranges align with the b128 return order (t0..t3), so each
// sub-chain starts as soon as its quarter of the h-vector lands. Combine
// via a 2-level add tree (8 v_add_f32, +16 cyc issue) — replaces the
// 20-deep serial fdot2 chain (~180-240 cyc of the 420-cyc/step spine).
// f32 reassociation only; weights/biases identical. Trailing wavefront
// fence replaces __syncthreads [R10] — compile-time LDS ordering only.
#define STEP(PAR, XQ, IDX)                                                   \
    {                                                                        \
        const uint4* hv = (const uint4*)&hbuf16[PAR][half * 32];             \
        uint4 t0 = hv[0], t1 = hv[1], t2 = hv[2], t3 = hv[3];                \
        v2h hj[16];                                                          \
        __builtin_memcpy(&hj[0], &t0, 16);                                   \
        __builtin_memcpy(&hj[4], &t1, 16);                                   \
        __builtin_memcpy(&hj[8], &t2, 16);                                   \
        __builtin_memcpy(&hj[12], &t3, 16);                                  \
        v2h xc[5];                                                           \
        _Pragma("unroll")                                                    \
        for (int pp = 0; pp < 5; ++pp) {                                     \
            unsigned w = ((const unsigned*)&XQ[pp])[IDX];                    \
            __builtin_memcpy(&xc[pp], &w, 4);                                \
        }                                                                    \
        float ar0 = brf, az0 = bzf, ai = bif, ah0 = bhf;                     \
        _Pragma("unroll")                                                    \
        for (int d = 0; d < 5; ++d) {                                        \
            ar0 = __builtin_amdgcn_fdot2(wir[d], xc[d], ar0, false);         \
            az0 = __builtin_amdgcn_fdot2(wiz[d], xc[d], az0, false);         \
            ai  = __builtin_amdgcn_fdot2(win[d], xc[d], ai, false);          \
        }                                                                    \
        float ar1 = 0.0f, ar2 = 0.0f, ar3 = 0.0f;                            \
        float az1 = 0.0f, az2 = 0.0f, az3 = 0.0f;                            \
        float ah1 = 0.0f, ah2 = 0.0f;                                        \
        _Pragma("unroll")                                                    \
        for (int j = 0; j < 5; ++j) {                                        \
            ar1 = __builtin_amdgcn_fdot2(whr[j], hj[j], ar1, false);         \
            az1 = __builtin_amdgcn_fdot2(whz[j], hj[j], az1, false);         \
            ah0 = __builtin_amdgcn_fdot2(whn[j], hj[j], ah0, false);         \
        }                                                                    \
        _Pragma("unroll")                                                    \
        for (int j = 5; j < 10; ++j) {                                       \
            ar2 = __builtin_amdgcn_fdot2(whr[j], hj[j], ar2, false);         \
            az2 = __builtin_amdgcn_fdot2(whz[j], hj[j], az2, false);         \
            ah1 = __builtin_amdgcn_fdot2(whn[j], hj[j], ah1, false);         \
        }                                                                    \
        _Pragma("unroll")                                                    \
        for (int j = 10; j < 15; ++j) {                                      \
            ar3 = __builtin_amdgcn_fdot2(whr[j], hj[j], ar3, false);         \
            az3 = __builtin_amdgcn_fdot2(whz[j], hj[j], az3, false);         \
            ah2 = __builtin_amdgcn_fdot2(whn[j], hj[j], ah2, false);         \
        }                                                                    \
        float ar = (ar0 + ar1) + (ar2 + ar3);                                \
        float az = (az0 + az1) + (az2 + az3);                                \
        float ah = (ah0 + ah1) + ah2;                                        \
        float er = __builtin_amdgcn_exp2f(ar);                               \
        float ez = __builtin_amdgcn_exp2f(az);                               \
        float rg = frcp(1.0f + er);                                          \
        float zg = frcp(1.0f + ez);                                          \
        float ng =                                                           \
            2.0f * frcp(1.0f + __builtin_amdgcn_exp2f(ai + rg * ah)) - 1.0f; \
        h = ng + zg * (h - ng);                                              \
        hbuf16[(PAR) ^ 1][half * 32 + k] = (_Float16)h;                      \
        __builtin_amdgcn_fence(__ATOMIC_ACQ_REL, "wavefront");               \
    }

// Kernel 2: GRU recurrence — full-dot mapping (R9+), 2 batches per wave,
// 1024 single-wave blocks. Lane k (k<30) computes the complete gates for
// unit k of its half's batch. h state stays f32 in registers; LDS broadcast
// copy is f16. amdgpu_waves_per_eu(1,1) [R6/R9]: pressure ceiling = the
// 1 wave/SIMD the grid supplies -> weights stay arch-resident.
__attribute__((amdgpu_waves_per_eu(1, 1)))
__global__ void __launch_bounds__(64)
gru_kernel(const _Float16* __restrict__ xpair,
           const float* __restrict__ W_ih,   // [90,10]
           const float* __restrict__ W_hh,   // [90,30]
           const float* __restrict__ b_ih,   // [90]
           const float* __restrict__ b_hh,   // [90]
           const float* __restrict__ W_out,  // [1,30]
           const float* __restrict__ b_out,  // [1]
           float* __restrict__ out) {
    __shared__ __align__(16) _Float16 hbuf16[2][64];
    const int lane = threadIdx.x;
    const int half = lane >> 5;
    const int k    = lane & 31;
    const bool active = (k < HID);
    const int kk = active ? k : (HID - 1);
    const int b = blockIdx.x * 2 + half;

    const float SRZ = -LOG2E;          // sigmoid(x) = rcp(1+exp2(-L x))
    const float SN  = -2.0f * LOG2E;   // tanh(u) = 2 rcp(1+exp2(-2L u)) - 1

    // hh weights: 15 v2h (j-pairs) per gate, prescaled in f32 then RNE->f16.
    v2h whr[15], whz[15], whn[15];
    {
        const float2* Rr = (const float2*)&W_hh[(0 * HID + kk) * HID];
        const float2* Rz = (const float2*)&W_hh[(1 * HID + kk) * HID];
        const float2* Rn = (const float2*)&W_hh[(2 * HID + kk) * HID];
#pragma unroll
        for (int j = 0; j < 15; ++j) {
            float2 tr = Rr[j], tz = Rz[j], tn = Rn[j];
            whr[j] = (v2h){(_Float16)(tr.x * SRZ), (_Float16)(tr.y * SRZ)};
            whz[j] = (v2h){(_Float16)(tz.x * SRZ), (_Float16)(tz.y * SRZ)};
            whn[j] = (v2h){(_Float16)(tn.x * SN),  (_Float16)(tn.y * SN)};
        }
    }
    // ih weights: 5 v2h per gate (d-pairs match xpair layout).
    v2h wir[5], wiz[5], win[5];
    {
        const float2* Rr = (const float2*)&W_ih[(0 * HID + kk) * NF];
        const float2* Rz = (const float2*)&W_ih[(1 * HID + kk) * NF];
        const float2* Rn = (const float2*)&W_ih[(2 * HID + kk) * NF];
#pragma unroll
        for (int d = 0; d < 5; ++d) {
            float2 tr = Rr[d], tz = Rz[d], tn = Rn[d];
            wir[d] = (v2h){(_Float16)(tr.x * SRZ), (_Float16)(tr.y * SRZ)};
            wiz[d] = (v2h){(_Float16)(tz.x * SRZ), (_Float16)(tz.y * SRZ)};
            win[d] = (v2h){(_Float16)(tn.x * SN),  (_Float16)(tn.y * SN)};
        }
    }
    // Biases (prescaled, f32 — fdot2's accumulator seed).
    const float brf = SRZ * (b_ih[0 * HID + kk] + b_hh[0 * HID + kk]);
    const float bzf = SRZ * (b_ih[1 * HID + kk] + b_hh[1 * HID + kk]);
    const float bif = SN * b_ih[2 * HID + kk];  // n biases stay split:
    const float bhf = SN * b_hh[2 * HID + kk];  // n uses ai + rg*ah

    // 5 chunk streams: xa[p][c] = uint4 = d-pair (2p,2p+1), steps 4c..4c+3
    const _Float16* xb = xpair + (long)b * FEAT_PER_B;
    const uint4* xa[5];
#pragma unroll
    for (int p = 0; p < 5; ++p) xa[p] = (const uint4*)(xb + p * 3072);

    hbuf16[0][lane] = (_Float16)0.0f;
    hbuf16[1][lane] = (_Float16)0.0f;
    __builtin_amdgcn_fence(__ATOMIC_ACQ_REL, "wavefront");

    float h = 0.0f;
    uint4 xq0[5], xq1[5];
#pragma unroll
    for (int p = 0; p < 5; ++p) xq0[p] = xa[p][0];

    // 384 chunks of 4 steps, ping-pong pairs (xq0/xq1 alternate roles — no
    // register rotation [R18]). 384 is even; prefetch c2+1 is always in
    // range, tail prefetch c2+2 clamps to 383.
    for (int c2 = 0; c2 < 384; c2 += 2) {
#pragma unroll
        for (int p = 0; p < 5; ++p) xq1[p] = xa[p][c2 + 1];
        STEP(0, xq0, 0);
        STEP(1, xq0, 1);
        STEP(0, xq0, 2);
        STEP(1, xq0, 3);
        const int cn = (c2 + 2 < 384) ? (c2 + 2) : 383;
#pragma unroll
        for (int p = 0; p < 5; ++p) xq0[p] = xa[p][cn];
        STEP(0, xq1, 0);
        STEP(1, xq1, 1);
        STEP(0, xq1, 2);
        STEP(1, xq1, 3);
    }

    // out[b] = relu(h . W_out + b_out), reduced within each 32-lane half
    float v = active ? h * W_out[kk] : 0.0f;
#pragma unroll
    for (int off = 16; off; off >>= 1) v += __shfl_xor(v, off, 32);
    if (k == 0) {
        float o = v + b_out[0];
        out[b] = o > 0.0f ? o : 0.0f;
    }
}

extern "C" void kernel_launch(void* const* d_in, const int* in_sizes, int n_in,
                              void* d_out, int out_size, void* d_ws, size_t ws_size,
                              hipStream_t stream) {
    const int* atom_i   = (const int*)d_in[0];
    const int* atom_j   = (const int*)d_in[1];
    const float* dist   = (const float*)d_in[2];
    const float* emb    = (const float*)d_in[3];
    const float* W_ih   = (const float*)d_in[4];
    const float* W_hh   = (const float*)d_in[5];
    const float* b_ih   = (const float*)d_in[6];
    const float* b_hh   = (const float*)d_in[7];
    const float* W_out  = (const float*)d_in[8];
    const float* b_out  = (const float*)d_in[9];
    float* out = (float*)d_out;
    _Float16* xpair = (_Float16*)d_ws;   // 62,914,560 B

    feat_kernel<<<BATCH, 512, 0, stream>>>(atom_i, atom_j, dist, emb,
                                           (uint4*)xpair);
    gru_kernel<<<BATCH / 2, 64, 0, stream>>>(xpair, W_ih, W_hh, b_ih, b_hh,
                                             W_out, b_out, out);
}